// Round 1
// baseline (211.692 us; speedup 1.0000x reference)
//
#include <hip/hip_runtime.h>

#define NB 256
#define NO 10
#define NI 1152
#define NK 8
#define ND 16
#define IC 16

typedef unsigned short u16;
typedef unsigned int u32;

__device__ __forceinline__ float bf2f(u32 hi){ return __uint_as_float(hi << 16); }
__device__ __forceinline__ u16 f2bf(float f){
  u32 u = __float_as_uint(f);
  return (u16)((u + 0x7FFFu + ((u >> 16) & 1u)) >> 16);  // RNE
}

// xT[(i*NK+k)*NB + b] = x[(b*NI+i)*NK + k]
__global__ __launch_bounds__(256) void k_transpose(const float* __restrict__ x,
                                                   float* __restrict__ xT){
  __shared__ float tile[32][33];
  int m0 = blockIdx.x * 32;   // ik index
  int b0 = blockIdx.y * 32;   // b index
  int tx = threadIdx.x, ty = threadIdx.y;
  #pragma unroll
  for (int r = 0; r < 32; r += 8)
    tile[ty + r][tx] = x[(size_t)(b0 + ty + r) * (NI * NK) + (m0 + tx)];
  __syncthreads();
  #pragma unroll
  for (int r = 0; r < 32; r += 8)
    xT[(size_t)(m0 + ty + r) * NB + (b0 + tx)] = tile[tx][ty + r];
}

// u[((o*NI+i)*NB + b)*ND + d] = sum_k W[((o*NI+i)*ND+d)*NK+k] * x[b,i,k]   (bf16)
__global__ __launch_bounds__(256) void k_einsum(const float* __restrict__ xT,
                                                const float* __restrict__ W,
                                                u16* __restrict__ u){
  __shared__ float Ws[IC * ND * NK];
  int o = blockIdx.y, i0 = blockIdx.x * IC, b = threadIdx.x;
  const float* Wg = W + ((size_t)o * NI + i0) * ND * NK;
  for (int t = threadIdx.x; t < IC * ND * NK; t += 256) Ws[t] = Wg[t];
  __syncthreads();
  for (int ii = 0; ii < IC; ++ii){
    int i = i0 + ii;
    float xr[NK];
    #pragma unroll
    for (int k = 0; k < NK; ++k) xr[k] = xT[((size_t)i * NK + k) * NB + b];
    u32 pk[8];
    #pragma unroll
    for (int j = 0; j < 8; ++j){
      float a0 = 0.f, a1 = 0.f;
      #pragma unroll
      for (int k = 0; k < NK; ++k){
        a0 = fmaf(Ws[(ii * ND + 2 * j) * NK + k], xr[k], a0);
        a1 = fmaf(Ws[(ii * ND + 2 * j + 1) * NK + k], xr[k], a1);
      }
      pk[j] = (u32)f2bf(a0) | ((u32)f2bf(a1) << 16);
    }
    uint4* dst = reinterpret_cast<uint4*>(u + (((size_t)o * NI + i) * NB + b) * ND);
    dst[0] = make_uint4(pk[0], pk[1], pk[2], pk[3]);
    dst[1] = make_uint4(pk[4], pk[5], pk[6], pk[7]);
  }
}

// C[o][i][b] = softmax over o of L[o][i][b]
__global__ __launch_bounds__(256) void k_c(const float* __restrict__ L,
                                           float* __restrict__ C){
  int i = blockIdx.x, b = threadIdx.x;
  size_t base = (size_t)i * NB + b;
  float l[NO];
  #pragma unroll
  for (int o = 0; o < NO; ++o) l[o] = L[(size_t)o * NI * NB + base];
  float m = l[0];
  #pragma unroll
  for (int o = 1; o < NO; ++o) m = fmaxf(m, l[o]);
  float den = 0.f;
  #pragma unroll
  for (int o = 0; o < NO; ++o){ l[o] = __expf(l[o] - m); den += l[o]; }
  float inv = 1.f / den;
  #pragma unroll
  for (int o = 0; o < NO; ++o) C[(size_t)o * NI * NB + base] = l[o] * inv;
}

template<bool RC>
__device__ __forceinline__ void get_u(float* uu, const u16* __restrict__ u,
                                      const float* __restrict__ xT,
                                      const float* Ws, int o, int i, int ii, int b){
  if constexpr (RC){
    float xr[NK];
    #pragma unroll
    for (int k = 0; k < NK; ++k) xr[k] = xT[((size_t)i * NK + k) * NB + b];
    #pragma unroll
    for (int d = 0; d < ND; ++d){
      float a = 0.f;
      #pragma unroll
      for (int k = 0; k < NK; ++k) a = fmaf(Ws[(ii * ND + d) * NK + k], xr[k], a);
      uu[d] = a;
    }
  } else {
    const uint4* up = reinterpret_cast<const uint4*>(u + (((size_t)o * NI + i) * NB + b) * ND);
    uint4 a0 = up[0], a1 = up[1];
    u32 pk[8] = {a0.x, a0.y, a0.z, a0.w, a1.x, a1.y, a1.z, a1.w};
    #pragma unroll
    for (int j = 0; j < 8; ++j){
      uu[2 * j]     = bf2f(pk[j] & 0xFFFFu);
      uu[2 * j + 1] = bf2f(pk[j] >> 16);
    }
  }
}

// S[o][d][b] += sum_{i in chunk} C[o][i][b] * u[o][i][b][d]
template<bool RC>
__global__ __launch_bounds__(256) void k_S_t(const float* __restrict__ C,
                                             const u16* __restrict__ u,
                                             const float* __restrict__ xT,
                                             const float* __restrict__ W,
                                             float* __restrict__ S){
  __shared__ float Ws[IC * ND * NK];
  int o = blockIdx.y, i0 = blockIdx.x * IC, b = threadIdx.x;
  if constexpr (RC){
    const float* Wg = W + ((size_t)o * NI + i0) * ND * NK;
    for (int t = threadIdx.x; t < IC * ND * NK; t += 256) Ws[t] = Wg[t];
    __syncthreads();
  }
  float acc[ND];
  #pragma unroll
  for (int d = 0; d < ND; ++d) acc[d] = 0.f;
  for (int ii = 0; ii < IC; ++ii){
    int i = i0 + ii;
    float c = C[((size_t)o * NI + i) * NB + b];
    float uu[ND];
    get_u<RC>(uu, u, xT, Ws, o, i, ii, b);
    #pragma unroll
    for (int d = 0; d < ND; ++d) acc[d] = fmaf(c, uu[d], acc[d]);
  }
  #pragma unroll
  for (int d = 0; d < ND; ++d)
    atomicAdd(&S[((size_t)o * ND + d) * NB + b], acc[d]);
}

// L[o][i][b] += (t2/(1+t2)) * (u·t) / (sqrt(t2)+eps),  t = S - u_i (per-element scalars only)
template<bool RC>
__global__ __launch_bounds__(256) void k_dot_t(const u16* __restrict__ u,
                                               const float* __restrict__ xT,
                                               const float* __restrict__ W,
                                               const float* __restrict__ S,
                                               float* __restrict__ L){
  __shared__ float Ws[IC * ND * NK];
  int o = blockIdx.y, i0 = blockIdx.x * IC, b = threadIdx.x;
  if constexpr (RC){
    const float* Wg = W + ((size_t)o * NI + i0) * ND * NK;
    for (int t = threadIdx.x; t < IC * ND * NK; t += 256) Ws[t] = Wg[t];
    __syncthreads();
  }
  float s[ND], s2 = 0.f;
  #pragma unroll
  for (int d = 0; d < ND; ++d){
    s[d] = S[((size_t)o * ND + d) * NB + b];
    s2 = fmaf(s[d], s[d], s2);
  }
  for (int ii = 0; ii < IC; ++ii){
    int i = i0 + ii;
    float uu[ND];
    get_u<RC>(uu, u, xT, Ws, o, i, ii, b);
    float dot = 0.f, usq = 0.f;
    #pragma unroll
    for (int d = 0; d < ND; ++d){
      dot = fmaf(uu[d], s[d], dot);
      usq = fmaf(uu[d], uu[d], usq);
    }
    float t2 = fmaxf(s2 - 2.f * dot + usq, 0.f);
    float ut = dot - usq;
    float db = (t2 / (1.f + t2)) * ut / (sqrtf(t2) + 1e-8f);
    L[((size_t)o * NI + i) * NB + b] += db;
  }
}

// out[b][o][d] = squash(S[b][o][:])
__global__ __launch_bounds__(256) void k_final(const float* __restrict__ S,
                                               float* __restrict__ out){
  int o = blockIdx.x, b = threadIdx.x;
  float s[ND], s2 = 0.f;
  #pragma unroll
  for (int d = 0; d < ND; ++d){
    s[d] = S[((size_t)o * ND + d) * NB + b];
    s2 = fmaf(s[d], s[d], s2);
  }
  float sc = (s2 / (1.f + s2)) / (sqrtf(s2) + 1e-8f);
  #pragma unroll
  for (int d = 0; d < ND; ++d) out[((size_t)b * NO + o) * ND + d] = s[d] * sc;
}

extern "C" void kernel_launch(void* const* d_in, const int* in_sizes, int n_in,
                              void* d_out, int out_size, void* d_ws, size_t ws_size,
                              hipStream_t stream){
  const float* x = (const float*)d_in[0];
  // d_in[1] (y) is unused by the reference computation.
  const float* W = (const float*)d_in[2];
  float* out = (float*)d_out;
  char* ws = (char*)d_ws;

  const size_t xT_b = (size_t)NI * NK * NB * sizeof(float);      // 9.4 MB
  const size_t u_b  = (size_t)NO * NI * NB * ND * sizeof(u16);   // 94.4 MB
  const size_t L_b  = (size_t)NO * NI * NB * sizeof(float);      // 11.8 MB
  const size_t S_b  = (size_t)NO * ND * NB * sizeof(float);      // 160 KB

  bool stored = ws_size >= xT_b + u_b + 2 * L_b + S_b;

  size_t off = 0;
  float* xT = (float*)(ws + off); off += xT_b;
  u16* u = nullptr;
  if (stored){ u = (u16*)(ws + off); off += u_b; }
  float* L = (float*)(ws + off); off += L_b;
  float* C = (float*)(ws + off); off += L_b;
  float* S = (float*)(ws + off); off += S_b;

  hipMemsetAsync(L, 0, L_b, stream);
  k_transpose<<<dim3((NI * NK) / 32, NB / 32), dim3(32, 8), 0, stream>>>(x, xT);
  if (stored)
    k_einsum<<<dim3(NI / IC, NO), 256, 0, stream>>>(xT, W, u);

  for (int it = 0; it < 3; ++it){
    k_c<<<dim3(NI), 256, 0, stream>>>(L, C);
    hipMemsetAsync(S, 0, S_b, stream);
    if (stored) k_S_t<false><<<dim3(NI / IC, NO), 256, 0, stream>>>(C, u, xT, W, S);
    else        k_S_t<true ><<<dim3(NI / IC, NO), 256, 0, stream>>>(C, u, xT, W, S);
    if (it < 2){
      if (stored) k_dot_t<false><<<dim3(NI / IC, NO), 256, 0, stream>>>(u, xT, W, S, L);
      else        k_dot_t<true ><<<dim3(NI / IC, NO), 256, 0, stream>>>(u, xT, W, S, L);
    }
  }
  k_final<<<dim3(NO), 256, 0, stream>>>(S, out);
}